// Round 4
// baseline (202.977 us; speedup 1.0000x reference)
//
#include <hip/hip_runtime.h>
#include <stdint.h>

#define N_NODES 2048
#define N_EDGES 4096
#define N_GRAPH 16
#define IN_DIM  11
#define HID     128
#define E_DIMF  6
#define EDGE_H  64
#define NSLICE  65            // 64 h-slices + 1 bias slice
#define ZCOLS   (NSLICE*HID)  // 8320
#define BN_EPS  1e-5f

typedef __attribute__((ext_vector_type(8))) short short8;
typedef __attribute__((ext_vector_type(4))) float f32x4;

static __device__ __forceinline__ float bf2f(unsigned short u) {
  union { float f; uint32_t i; } x; x.i = ((uint32_t)u) << 16; return x.f;
}
static __device__ __forceinline__ unsigned short f2bf(float f) {
  union { float f; uint32_t i; } x; x.f = f;
  uint32_t i = x.i;
  return (unsigned short)((i + 0x7FFFu + ((i >> 16) & 1u)) >> 16);
}

// ---------------- CSR build ----------------
__global__ void calc_deg_i(const int* __restrict__ dst, int* __restrict__ degi) {
  int e = blockIdx.x * 256 + threadIdx.x;
  if (e < N_EDGES) atomicAdd(&degi[dst[e]], 1);
}

__global__ __launch_bounds__(256) void build_offsets(const int* __restrict__ degi,
                                                     int* __restrict__ roff,
                                                     int* __restrict__ cursor) {
  __shared__ int part[256];
  int t = threadIdx.x;
  int base = t * 8;
  int loc[8];
  int s = 0;
#pragma unroll
  for (int j = 0; j < 8; ++j) { loc[j] = s; s += degi[base + j]; }
  part[t] = s;
  __syncthreads();
  int pre = 0;
  for (int i = 0; i < t; ++i) pre += part[i];
#pragma unroll
  for (int j = 0; j < 8; ++j) {
    int v = pre + loc[j];
    roff[base + j] = v;
    cursor[base + j] = v;
  }
  if (t == 255) roff[N_NODES] = pre + s;
}

__global__ void scatter_edges(const int* __restrict__ dst, int* __restrict__ cursor,
                              int* __restrict__ elist) {
  int e = blockIdx.x * 256 + threadIdx.x;
  if (e < N_EDGES) {
    int pos = atomicAdd(&cursor[dst[e]], 1);
    elist[pos] = e;
  }
}

// ---- fused prep: weight transposes (bf16, [(k,o)][i]) + layer-0 input cast ----
// grid (65, 5): y=0 -> layer0 W (KP=32, din=11); y=1..3 -> layer y-1 of eW2
// (KP=128); y=4 -> xb0 cast (grid-stride over 65 blocks).
__global__ __launch_bounds__(256) void prep(const float* __restrict__ W2_0,
                                            const float* __restrict__ b2_0,
                                            const float* __restrict__ W2L,
                                            const float* __restrict__ b2L,
                                            const float* __restrict__ h_in,
                                            unsigned short* __restrict__ WbT0,
                                            unsigned short* __restrict__ WbTL,
                                            unsigned short* __restrict__ xb0) {
  const int y = blockIdx.y, t = threadIdx.x;
  if (y == 4) {
    for (int idx = blockIdx.x * 256 + t; idx < N_NODES * 32; idx += 65 * 256) {
      int n = idx >> 5, i = idx & 31;
      xb0[idx] = f2bf(i < IN_DIM ? h_in[n * IN_DIM + i] : 0.0f);
    }
    return;
  }
  __shared__ unsigned short tile[128 * 130];  // [i][o], pad -> odd bank stride
  const int k = blockIdx.x;  // 0..64
  if (y == 0) {
    const float* src = (k < 64) ? (W2_0 + (size_t)k * IN_DIM * HID) : b2_0;
    for (int j = t; j < IN_DIM * HID; j += 256) {
      int i = j >> 7, o = j & 127;
      tile[i * 130 + o] = f2bf(src[j]);
    }
    __syncthreads();
    for (int j = t; j < HID * 32; j += 256) {
      int o = j >> 5, i = j & 31;
      WbT0[((size_t)k * HID + o) * 32 + i] =
          (i < IN_DIM) ? tile[i * 130 + o] : (unsigned short)0;
    }
  } else {
    const int l = y - 1;
    const float* src = (k < 64) ? (W2L + ((size_t)l * 64 + k) * (HID * HID))
                                : (b2L + (size_t)l * (HID * HID));
    unsigned short* dstp = WbTL + (size_t)l * ZCOLS * HID;
    for (int j = t; j < HID * HID; j += 256) {
      int i = j >> 7, o = j & 127;
      tile[i * 130 + o] = f2bf(src[j]);
    }
    __syncthreads();
    for (int j = t; j < HID * HID; j += 256) {
      int o = j >> 7, i = j & 127;
      dstp[((size_t)k * HID + o) * HID + i] = tile[i * 130 + o];
    }
  }
}

// ---------------- Z GEMM: Z[n, ko] = sum_i xb[n,i] * WbT[ko,i] ----------------
// Swapped-operand MFMA: acc = mfma(b, a) -> D[ko][node]; thread holds 4
// consecutive ko at fixed node -> packed 8B stores, 4 stores/row fill a full
// 128B line.
template <int KP, int SWZ>
__global__ __launch_bounds__(256) void gemm_z(const unsigned short* __restrict__ Xb,
                                              const unsigned short* __restrict__ WbT,
                                              unsigned short* __restrict__ Z) {
  extern __shared__ unsigned short lds[];
  unsigned short* Al = lds;              // [128][KP]
  unsigned short* Bl = lds + 128 * KP;   // [128][KP] (row = ko)
  const int nb = blockIdx.x;   // ko tile: 0..64
  const int mb = blockIdx.y;   // node tile: 0..15
  const int t = threadIdx.x;
  const int ROWB = KP * 2;
  const int NCH = 128 * ROWB / 16;
  const unsigned short* Asrc = Xb + (size_t)mb * 128 * KP;
  const unsigned short* Bsrc = WbT + (size_t)nb * 128 * KP;
  for (int c = t; c < NCH; c += 256) {
    int off = c * 16;
    int row = off / ROWB;
    int kb = off % ROWB;
    int dsto = row * ROWB + (kb ^ ((row & SWZ) << 4));
    *(uint4*)((char*)Al + dsto) = *(const uint4*)((const char*)Asrc + off);
    *(uint4*)((char*)Bl + dsto) = *(const uint4*)((const char*)Bsrc + off);
  }
  __syncthreads();

  const int w = t >> 6, l = t & 63;
  const int wm = (w >> 1) * 64, wn = (w & 1) * 64;
  const int lr = l & 15, lh = l >> 4;
  f32x4 acc[4][4] = {};
#pragma unroll
  for (int kk = 0; kk < KP; kk += 32) {
    short8 a[4], b[4];
    const int kb = (kk + lh * 8) * 2;
#pragma unroll
    for (int mi = 0; mi < 4; ++mi) {
      int row = wm + mi * 16 + lr;
      int addr = row * ROWB + (kb ^ ((row & SWZ) << 4));
      a[mi] = *(const short8*)((const char*)Al + addr);
    }
#pragma unroll
    for (int ni = 0; ni < 4; ++ni) {
      int col = wn + ni * 16 + lr;
      int addr = col * ROWB + (kb ^ ((col & SWZ) << 4));
      b[ni] = *(const short8*)((const char*)Bl + addr);
    }
#pragma unroll
    for (int mi = 0; mi < 4; ++mi)
#pragma unroll
      for (int ni = 0; ni < 4; ++ni)
        acc[mi][ni] = __builtin_amdgcn_mfma_f32_16x16x32_bf16(b[ni], a[mi], acc[mi][ni], 0, 0, 0);
  }
  // D[ko][node]: ko = wn + ni*16 + lh*4 + r, node = wm + mi*16 + lr
#pragma unroll
  for (int mi = 0; mi < 4; ++mi) {
    const int node = mb * 128 + wm + mi * 16 + lr;
    unsigned short* zp = Z + (size_t)node * ZCOLS + nb * 128 + wn + lh * 4;
#pragma unroll
    for (int ni = 0; ni < 4; ++ni) {
      ushort4 pk;
      pk.x = f2bf(acc[mi][ni][0]);
      pk.y = f2bf(acc[mi][ni][1]);
      pk.z = f2bf(acc[mi][ni][2]);
      pk.w = f2bf(acc[mi][ni][3]);
      *(ushort4*)(zp + ni * 16) = pk;
    }
  }
}

// ------- per-node gather: edge-MLP + contract + mean + bias + ReLU + BN -------
// block = node (grid 2048), 128 threads: cg = t&15 (8 channels o=cg*8..+8),
// kg = t>>4 (8 k-values). short8 (16B) coalesced Z reads; kg-reduce via LDS
// once per node.
template <int LAST>
__global__ __launch_bounds__(128) void node_gather(
    const float* __restrict__ efeat, const float* __restrict__ W1,
    const float* __restrict__ b1, const unsigned short* __restrict__ Z,
    const int* __restrict__ elist, const int* __restrict__ roff,
    const int* __restrict__ src,
    const float* __restrict__ bias, const float* __restrict__ gamma,
    const float* __restrict__ beta, const float* __restrict__ mean,
    const float* __restrict__ var,
    unsigned short* __restrict__ xbout,
    const int* __restrict__ ng, float* __restrict__ gsum,
    unsigned int* __restrict__ gmax, float* __restrict__ gcnt) {
  const int n = blockIdx.x, t = threadIdx.x;
  const int cg = t & 15, kg = t >> 4;
  const int start = roff[n], end = roff[n + 1];
  __shared__ float hs[EDGE_H];
  __shared__ float red[128][9];  // pad 9 -> conflict-light
  float acc8[8] = {};
  for (int idx = start; idx < end; ++idx) {
    const int e = elist[idx];
    __syncthreads();
    if (t < EDGE_H) {
      float a = b1[t];
#pragma unroll
      for (int j = 0; j < E_DIMF; ++j) a += efeat[e * E_DIMF + j] * W1[j * EDGE_H + t];
      hs[t] = fmaxf(a, 0.f);
    }
    __syncthreads();
    const unsigned short* zr = Z + (size_t)src[e] * ZCOLS + cg * 8;
#pragma unroll
    for (int kk = 0; kk < 8; ++kk) {
      const int k = kg * 8 + kk;
      short8 v = *(const short8*)(zr + k * HID);
      const float hk = hs[k];
#pragma unroll
      for (int j = 0; j < 8; ++j) acc8[j] += hk * bf2f((unsigned short)v[j]);
    }
    if (kg == 0) {  // bias slice k=64, h=1
      short8 v = *(const short8*)(zr + 64 * HID);
#pragma unroll
      for (int j = 0; j < 8; ++j) acc8[j] += bf2f((unsigned short)v[j]);
    }
  }
#pragma unroll
  for (int j = 0; j < 8; ++j) red[t][j] = acc8[j];
  __syncthreads();
  const int o = t;
  float s = 0.f;
#pragma unroll
  for (int k2 = 0; k2 < 8; ++k2) s += red[k2 * 16 + (o >> 3)][o & 7];
  const int dg = end - start;
  float v = s / (float)(dg > 0 ? dg : 1) + bias[o];
  v = fmaxf(v, 0.f);
  v = (v - mean[o]) * rsqrtf(var[o] + BN_EPS) * gamma[o] + beta[o];
  if (!LAST) {
    xbout[n * HID + o] = f2bf(v);
  } else {
    const int g = ng[n];
    atomicAdd(&gsum[g * HID + o], v);
    unsigned int u = __float_as_uint(v);
    unsigned int key = (u & 0x80000000u) ? ~u : (u | 0x80000000u);
    atomicMax(&gmax[g * HID + o], key);
    if (o == 0) atomicAdd(&gcnt[g], 1.f);
  }
}

// ---------------- output BN + max decode ----------------
__global__ void out_final(const float* __restrict__ gsum, const unsigned int* __restrict__ gmax,
                          const float* __restrict__ gcnt,
                          const float* __restrict__ g_out, const float* __restrict__ b_out,
                          const float* __restrict__ m_out, const float* __restrict__ v_out,
                          float* __restrict__ out) {
  int g = blockIdx.x, t = threadIdx.x;
  float hn = gsum[g * HID + t] / fmaxf(gcnt[g], 1.0f);
  hn = (hn - m_out[t]) * rsqrtf(v_out[t] + BN_EPS) * g_out[t] + b_out[t];
  unsigned int key = gmax[g * HID + t];
  unsigned int u = (key & 0x80000000u) ? (key ^ 0x80000000u) : ~key;
  out[g * 2 * HID + t] = hn;
  out[g * 2 * HID + HID + t] = __uint_as_float(u);
}

extern "C" void kernel_launch(void* const* d_in, const int* in_sizes, int n_in,
                              void* d_out, int out_size, void* d_ws, size_t ws_size,
                              hipStream_t stream) {
  const float* h_in   = (const float*)d_in[0];
  const float* e_in   = (const float*)d_in[1];
  const int*   src    = (const int*)d_in[2];
  const int*   dst    = (const int*)d_in[3];
  const int*   ng     = (const int*)d_in[4];
  const float* eW1_0  = (const float*)d_in[5];
  const float* eb1_0  = (const float*)d_in[6];
  const float* eW2_0  = (const float*)d_in[7];
  const float* eb2_0  = (const float*)d_in[8];
  const float* bias_0 = (const float*)d_in[9];
  const float* gamma_0= (const float*)d_in[10];
  const float* beta_0 = (const float*)d_in[11];
  const float* mean_0 = (const float*)d_in[12];
  const float* var_0  = (const float*)d_in[13];
  const float* eW1    = (const float*)d_in[14];
  const float* eb1    = (const float*)d_in[15];
  const float* eW2    = (const float*)d_in[16];
  const float* eb2    = (const float*)d_in[17];
  const float* biasL  = (const float*)d_in[18];
  const float* gammaL = (const float*)d_in[19];
  const float* betaL  = (const float*)d_in[20];
  const float* meanL  = (const float*)d_in[21];
  const float* varL   = (const float*)d_in[22];
  const float* g_out  = (const float*)d_in[23];
  const float* b_out  = (const float*)d_in[24];
  const float* m_out  = (const float*)d_in[25];
  const float* v_out  = (const float*)d_in[26];
  float* out = (float*)d_out;

  char* ws = (char*)d_ws;
  size_t off = 0;
  auto alloc = [&](size_t bytes) {
    void* p = ws + off;
    off = (off + bytes + 255) & ~(size_t)255;
    return p;
  };
  unsigned short* Z    = (unsigned short*)alloc((size_t)N_NODES * ZCOLS * 2);
  unsigned short* WbT0 = (unsigned short*)alloc((size_t)ZCOLS * 32 * 2);
  unsigned short* WbTL = (unsigned short*)alloc((size_t)3 * ZCOLS * HID * 2);
  unsigned short* xb0  = (unsigned short*)alloc((size_t)N_NODES * 32 * 2);
  unsigned short* xb   = (unsigned short*)alloc((size_t)N_NODES * HID * 2);
  // zero-region (single memset): gsum | gmax | gcnt | degi
  float* gsum          = (float*)alloc((size_t)N_GRAPH * HID * 4);
  unsigned int* gmax   = (unsigned int*)alloc((size_t)N_GRAPH * HID * 4);
  float* gcnt          = (float*)alloc((size_t)N_GRAPH * 4);
  int*   degi          = (int*)alloc((size_t)N_NODES * 4);
  size_t zbytes = (size_t)((char*)(degi + N_NODES) - (char*)gsum);
  int* roff            = (int*)alloc((size_t)(N_NODES + 1) * 4);
  int* cursor          = (int*)alloc((size_t)N_NODES * 4);
  int* elist           = (int*)alloc((size_t)N_EDGES * 4);

  // --- one-time per call ---
  hipMemsetAsync(gsum, 0, zbytes, stream);
  calc_deg_i<<<N_EDGES / 256, 256, 0, stream>>>(dst, degi);
  build_offsets<<<1, 256, 0, stream>>>(degi, roff, cursor);
  scatter_edges<<<N_EDGES / 256, 256, 0, stream>>>(dst, cursor, elist);
  prep<<<dim3(65, 5), 256, 0, stream>>>(eW2_0, eb2_0, eW2, eb2, h_in, WbT0, WbTL, xb0);

  // --- layer 0 (din=11, padded K=32) ---
  gemm_z<32, 3><<<dim3(65, 16), 256, 2 * 128 * 32 * 2, stream>>>(xb0, WbT0, Z);
  node_gather<0><<<N_NODES, 128, 0, stream>>>(e_in, eW1_0, eb1_0, Z, elist, roff, src,
                                              bias_0, gamma_0, beta_0, mean_0, var_0,
                                              xb, ng, gsum, gmax, gcnt);

  // --- layers 1..3 (din=128) ---
  for (int l = 0; l < 3; ++l) {
    gemm_z<128, 7><<<dim3(65, 16), 256, 2 * 128 * 128 * 2, stream>>>(
        xb, WbTL + (size_t)l * ZCOLS * HID, Z);
    if (l < 2) {
      node_gather<0><<<N_NODES, 128, 0, stream>>>(
          e_in, eW1 + l * E_DIMF * EDGE_H, eb1 + l * EDGE_H, Z, elist, roff, src,
          biasL + l * HID, gammaL + l * HID, betaL + l * HID, meanL + l * HID,
          varL + l * HID, xb, ng, gsum, gmax, gcnt);
    } else {
      node_gather<1><<<N_NODES, 128, 0, stream>>>(
          e_in, eW1 + l * E_DIMF * EDGE_H, eb1 + l * EDGE_H, Z, elist, roff, src,
          biasL + l * HID, gammaL + l * HID, betaL + l * HID, meanL + l * HID,
          varL + l * HID, xb, ng, gsum, gmax, gcnt);
    }
  }

  out_final<<<N_GRAPH, HID, 0, stream>>>(gsum, gmax, gcnt, g_out, b_out, m_out, v_out, out);
}

// Round 6
// 199.950 us; speedup vs baseline: 1.0151x; 1.0151x over previous
//
#include <hip/hip_runtime.h>
#include <hip/hip_cooperative_groups.h>
#include <stdint.h>

namespace cg = cooperative_groups;

#define N_NODES 2048
#define N_EDGES 4096
#define N_GRAPH 16
#define IN_DIM  11
#define HID     128
#define E_DIMF  6
#define EDGE_H  64
#define NSLICE  65            // 64 h-slices + 1 bias slice
#define ZCOLS   (NSLICE*HID)  // 8320
#define BN_EPS  1e-5f
#define MEGA_BLOCKS 256       // 1 block/CU -> co-residency guaranteed
#define MEGA_THREADS 512

typedef __attribute__((ext_vector_type(8))) short short8;
typedef __attribute__((ext_vector_type(4))) float f32x4;

static __device__ __forceinline__ float bf2f(unsigned short u) {
  union { float f; uint32_t i; } x; x.i = ((uint32_t)u) << 16; return x.f;
}
static __device__ __forceinline__ unsigned short f2bf(float f) {
  union { float f; uint32_t i; } x; x.f = f;
  uint32_t i = x.i;
  return (unsigned short)((i + 0x7FFFu + ((i >> 16) & 1u)) >> 16);
}

struct MegaP {
  const float *h_in, *e_in;
  const int *src, *dst, *ng;
  const float *eW1_0, *eb1_0, *eW2_0, *eb2_0;
  const float *bias_0, *gamma_0, *beta_0, *mean_0, *var_0;
  const float *eW1, *eb1, *eW2, *eb2;
  const float *biasL, *gammaL, *betaL, *meanL, *varL;
  const float *g_out, *b_out, *m_out, *v_out;
  float *out;
  unsigned short *Z, *WbT0, *WbTL, *xb0, *xb;
  float *gsum;
  unsigned int *gmax;
  float *gcnt;
  int *roff, *cursor, *elist;
};

// ================= mega (cooperative) device phases, 512 threads =============

// transpose one W2 slab into WbT layout [(k,o)][i] (bf16)
static __device__ void transpose_slab(const MegaP& p, int s, char* smem) {
  unsigned short* tile = (unsigned short*)smem;  // [128][130]
  const int t = threadIdx.x;
  if (s < 65) {  // layer 0, KP=32, din=11
    const int k = s;
    const float* srcp = (k < 64) ? (p.eW2_0 + (size_t)k * IN_DIM * HID) : p.eb2_0;
    for (int j = t; j < IN_DIM * HID; j += MEGA_THREADS) {
      int i = j >> 7, o = j & 127;
      tile[i * 130 + o] = f2bf(srcp[j]);
    }
    __syncthreads();
    for (int j = t; j < HID * 32; j += MEGA_THREADS) {
      int o = j >> 5, i = j & 31;
      p.WbT0[((size_t)k * HID + o) * 32 + i] =
          (i < IN_DIM) ? tile[i * 130 + o] : (unsigned short)0;
    }
    __syncthreads();
  } else {  // layers 1..3, KP=128
    const int sl = s - 65, l = sl / 65, k = sl % 65;
    const float* srcp = (k < 64) ? (p.eW2 + ((size_t)l * 64 + k) * (HID * HID))
                                 : (p.eb2 + (size_t)l * (HID * HID));
    unsigned short* dstp = p.WbTL + (size_t)l * ZCOLS * HID;
    for (int j = t; j < HID * HID; j += MEGA_THREADS) {
      int i = j >> 7, o = j & 127;
      tile[i * 130 + o] = f2bf(srcp[j]);
    }
    __syncthreads();
    for (int j = t; j < HID * HID; j += MEGA_THREADS) {
      int o = j >> 7, i = j & 127;
      dstp[((size_t)k * HID + o) * HID + i] = tile[i * 130 + o];
    }
    __syncthreads();
  }
}

// Z[n,ko] = sum_i Xb[n,i]*WbT[ko,i]; swapped-operand MFMA -> D[ko][node],
// packed 8B stores. 8 waves: 2(m)x4(n), each 64x32 of the 128x128 tile.
template <int KP, int SWZ>
static __device__ void gemm_phase(const unsigned short* Xb, const unsigned short* WbT,
                                  unsigned short* Z, char* smem) {
  unsigned short* Al = (unsigned short*)smem;   // [128][KP] node rows
  unsigned short* Bl = Al + 128 * KP;           // [128][KP] ko rows
  const int t = threadIdx.x;
  const int ROWB = KP * 2;
  const int NCH = 128 * ROWB / 16;
  const int w = t >> 6, l = t & 63;
  const int wm = (w >> 2) * 64, wn = (w & 3) * 32;
  const int lr = l & 15, lh = l >> 4;
  for (int tile = blockIdx.x; tile < 65 * 16; tile += gridDim.x) {
    const int nb = tile % 65, mb = tile / 65;
    const unsigned short* Asrc = Xb + (size_t)mb * 128 * KP;
    const unsigned short* Bsrc = WbT + (size_t)nb * 128 * KP;
    for (int c = t; c < NCH; c += MEGA_THREADS) {
      int off = c * 16;
      int row = off / ROWB;
      int kb = off % ROWB;
      int dsto = row * ROWB + (kb ^ ((row & SWZ) << 4));
      *(uint4*)((char*)Al + dsto) = *(const uint4*)((const char*)Asrc + off);
      *(uint4*)((char*)Bl + dsto) = *(const uint4*)((const char*)Bsrc + off);
    }
    __syncthreads();
    f32x4 acc[4][2] = {};
#pragma unroll
    for (int kk = 0; kk < KP; kk += 32) {
      short8 a[4], b[2];
      const int kb = (kk + lh * 8) * 2;
#pragma unroll
      for (int mi = 0; mi < 4; ++mi) {
        int row = wm + mi * 16 + lr;
        int addr = row * ROWB + (kb ^ ((row & SWZ) << 4));
        a[mi] = *(const short8*)((const char*)Al + addr);
      }
#pragma unroll
      for (int ni = 0; ni < 2; ++ni) {
        int col = wn + ni * 16 + lr;
        int addr = col * ROWB + (kb ^ ((col & SWZ) << 4));
        b[ni] = *(const short8*)((const char*)Bl + addr);
      }
#pragma unroll
      for (int mi = 0; mi < 4; ++mi)
#pragma unroll
        for (int ni = 0; ni < 2; ++ni)
          acc[mi][ni] = __builtin_amdgcn_mfma_f32_16x16x32_bf16(b[ni], a[mi], acc[mi][ni], 0, 0, 0);
    }
#pragma unroll
    for (int mi = 0; mi < 4; ++mi) {
      const int node = mb * 128 + wm + mi * 16 + lr;
      unsigned short* zp = Z + (size_t)node * ZCOLS + nb * 128 + wn + lh * 4;
#pragma unroll
      for (int ni = 0; ni < 2; ++ni) {
        ushort4 pk;
        pk.x = f2bf(acc[mi][ni][0]);
        pk.y = f2bf(acc[mi][ni][1]);
        pk.z = f2bf(acc[mi][ni][2]);
        pk.w = f2bf(acc[mi][ni][3]);
        *(ushort4*)(zp + ni * 16) = pk;
      }
    }
    __syncthreads();
  }
}

// gather: 4 nodes per block-iteration (4 thread-halves of 128).
// Per half: cgi = tt&15 (8 channels), kg = tt>>4 (8 k). Edge-MLP h recomputed
// per-thread (no per-edge barrier).
template <int LAST>
static __device__ void gather_phase(const MegaP& p, const float* W1, const float* b1,
                                    const float* bias, const float* gamma,
                                    const float* beta, const float* mean,
                                    const float* var, char* smem) {
  float* red = (float*)smem;  // [4][128][9]
  const int t = threadIdx.x;
  const int hh = t >> 7, tt = t & 127;
  const int cgi = tt & 15, kg = tt >> 4;
  for (int n0 = blockIdx.x * 4; n0 < N_NODES; n0 += gridDim.x * 4) {
    const int n = n0 + hh;
    const int start = p.roff[n], end = p.roff[n + 1];
    float acc8[8] = {};
    for (int idx = start; idx < end; ++idx) {
      const int e = p.elist[idx];
      float ef[E_DIMF];
#pragma unroll
      for (int j = 0; j < E_DIMF; ++j) ef[j] = p.e_in[e * E_DIMF + j];
      float hk[8];
#pragma unroll
      for (int kk = 0; kk < 8; ++kk) {
        const int k = kg * 8 + kk;
        float a = b1[k];
#pragma unroll
        for (int j = 0; j < E_DIMF; ++j) a += ef[j] * W1[j * EDGE_H + k];
        hk[kk] = fmaxf(a, 0.f);
      }
      const unsigned short* zr = p.Z + (size_t)p.src[e] * ZCOLS + cgi * 8;
#pragma unroll
      for (int kk = 0; kk < 8; ++kk) {
        short8 v = *(const short8*)(zr + (kg * 8 + kk) * HID);
        const float hv = hk[kk];
#pragma unroll
        for (int j = 0; j < 8; ++j) acc8[j] += hv * bf2f((unsigned short)v[j]);
      }
      if (kg == 0) {  // bias slice k=64, h=1
        short8 v = *(const short8*)(zr + 64 * HID);
#pragma unroll
        for (int j = 0; j < 8; ++j) acc8[j] += bf2f((unsigned short)v[j]);
      }
    }
    __syncthreads();  // guard red reuse from previous iteration
#pragma unroll
    for (int j = 0; j < 8; ++j) red[(hh * 128 + tt) * 9 + j] = acc8[j];
    __syncthreads();
    const int o = tt;
    float s = 0.f;
#pragma unroll
    for (int k2 = 0; k2 < 8; ++k2) s += red[(hh * 128 + k2 * 16 + (o >> 3)) * 9 + (o & 7)];
    const int dg = end - start;
    float v = s / (float)(dg > 0 ? dg : 1) + bias[o];
    v = fmaxf(v, 0.f);
    v = (v - mean[o]) * rsqrtf(var[o] + BN_EPS) * gamma[o] + beta[o];
    if (!LAST) {
      p.xb[n * HID + o] = f2bf(v);
    } else {
      const int g = p.ng[n];
      atomicAdd(&p.gsum[g * HID + o], v);
      unsigned int u = __float_as_uint(v);
      unsigned int key = (u & 0x80000000u) ? ~u : (u | 0x80000000u);
      atomicMax(&p.gmax[g * HID + o], key);
      if (o == 0) atomicAdd(&p.gcnt[g], 1.f);
    }
  }
}

static __device__ __forceinline__ void gsync(cg::grid_group& g) {
  __threadfence();
  g.sync();
  __threadfence();
}

__global__ __launch_bounds__(MEGA_THREADS, 2) void mega(MegaP p) {
  cg::grid_group grid = cg::this_grid();
  extern __shared__ char smem[];
  const int bid = blockIdx.x, t = threadIdx.x;
  const int NB = gridDim.x;

  // ---- P0: zero accums + xb0 cast + (block0: deg hist+scan) + transposes ----
  for (int i = bid * MEGA_THREADS + t; i < N_GRAPH * HID; i += NB * MEGA_THREADS) {
    p.gsum[i] = 0.f;
    p.gmax[i] = 0u;
  }
  if (bid == 1 && t < N_GRAPH) p.gcnt[t] = 0.f;
  for (int idx = bid * MEGA_THREADS + t; idx < N_NODES * 32; idx += NB * MEGA_THREADS) {
    int n = idx >> 5, i = idx & 31;
    p.xb0[idx] = f2bf(i < IN_DIM ? p.h_in[n * IN_DIM + i] : 0.f);
  }
  if (bid == 0) {
    // deg histogram in LDS + exclusive scan -> roff, cursor
    int* hist = (int*)smem;          // [2048]
    int* part = hist + N_NODES;      // [256]
    for (int i = t; i < N_NODES; i += MEGA_THREADS) hist[i] = 0;
    __syncthreads();
    for (int e = t; e < N_EDGES; e += MEGA_THREADS) atomicAdd(&hist[p.dst[e]], 1);
    __syncthreads();
    if (t < 256) {
      const int base = t * 8;
      int s = 0;
#pragma unroll
      for (int j = 0; j < 8; ++j) s += hist[base + j];
      part[t] = s;
    }
    __syncthreads();
    for (int d = 1; d < 256; d <<= 1) {  // Hillis-Steele inclusive scan
      int v = 0;
      if (t < 256) { v = part[t]; if (t >= d) v += part[t - d]; }
      __syncthreads();
      if (t < 256) part[t] = v;
      __syncthreads();
    }
    if (t < 256) {
      const int pre = (t == 0) ? 0 : part[t - 1];
      const int base = t * 8;
      int s = 0;
#pragma unroll
      for (int j = 0; j < 8; ++j) {
        p.roff[base + j] = pre + s;
        p.cursor[base + j] = pre + s;
        s += hist[base + j];
      }
      if (t == 255) p.roff[N_NODES] = pre + s;
    }
  } else {
    // 260 transpose slabs on blocks 1..NB-1
    for (int s = bid - 1; s < 260; s += NB - 1) transpose_slab(p, s, smem);
  }
  gsync(grid);

  // ---- P1: scatter edges + layer-0 GEMM ----
  for (int e = bid * MEGA_THREADS + t; e < N_EDGES; e += NB * MEGA_THREADS) {
    const int pos = atomicAdd(&p.cursor[p.dst[e]], 1);
    p.elist[pos] = e;
  }
  gemm_phase<32, 3>(p.xb0, p.WbT0, p.Z, smem);
  gsync(grid);

  // ---- P2: layer-0 gather ----
  gather_phase<0>(p, p.eW1_0, p.eb1_0, p.bias_0, p.gamma_0, p.beta_0,
                  p.mean_0, p.var_0, smem);
  gsync(grid);

  // ---- layers 1..3 ----
  for (int l = 0; l < 3; ++l) {
    gemm_phase<128, 7>(p.xb, p.WbTL + (size_t)l * ZCOLS * HID, p.Z, smem);
    gsync(grid);
    const float* W1 = p.eW1 + l * E_DIMF * EDGE_H;
    const float* b1 = p.eb1 + l * EDGE_H;
    if (l < 2)
      gather_phase<0>(p, W1, b1, p.biasL + l * HID, p.gammaL + l * HID,
                      p.betaL + l * HID, p.meanL + l * HID, p.varL + l * HID, smem);
    else
      gather_phase<1>(p, W1, b1, p.biasL + l * HID, p.gammaL + l * HID,
                      p.betaL + l * HID, p.meanL + l * HID, p.varL + l * HID, smem);
    gsync(grid);
  }

  // ---- final: output BN + max decode (blocks 0..3, 4 graphs each) ----
  if (bid < 4) {
    const int g = bid * 4 + (t >> 7), o = t & 127;
    float hn = p.gsum[g * HID + o] / fmaxf(p.gcnt[g], 1.f);
    hn = (hn - p.m_out[o]) * rsqrtf(p.v_out[o] + BN_EPS) * p.g_out[o] + p.b_out[o];
    const unsigned int key = p.gmax[g * HID + o];
    const unsigned int u = (key & 0x80000000u) ? (key ^ 0x80000000u) : ~key;
    p.out[g * 2 * HID + o] = hn;
    p.out[g * 2 * HID + HID + o] = __uint_as_float(u);
  }
}

// ===================== fallback path (verified R3 kernels) ====================

__global__ void calc_deg_i(const int* __restrict__ dst, int* __restrict__ degi) {
  int e = blockIdx.x * 256 + threadIdx.x;
  if (e < N_EDGES) atomicAdd(&degi[dst[e]], 1);
}

__global__ __launch_bounds__(256) void build_offsets(const int* __restrict__ degi,
                                                     int* __restrict__ roff,
                                                     int* __restrict__ cursor) {
  __shared__ int part[256];
  int t = threadIdx.x;
  int base = t * 8;
  int loc[8];
  int s = 0;
#pragma unroll
  for (int j = 0; j < 8; ++j) { loc[j] = s; s += degi[base + j]; }
  part[t] = s;
  __syncthreads();
  int pre = 0;
  for (int i = 0; i < t; ++i) pre += part[i];
#pragma unroll
  for (int j = 0; j < 8; ++j) {
    int v = pre + loc[j];
    roff[base + j] = v;
    cursor[base + j] = v;
  }
  if (t == 255) roff[N_NODES] = pre + s;
}

__global__ void scatter_edges(const int* __restrict__ dst, int* __restrict__ cursor,
                              int* __restrict__ elist) {
  int e = blockIdx.x * 256 + threadIdx.x;
  if (e < N_EDGES) {
    int pos = atomicAdd(&cursor[dst[e]], 1);
    elist[pos] = e;
  }
}

__global__ __launch_bounds__(256) void prep(const float* __restrict__ W2_0,
                                            const float* __restrict__ b2_0,
                                            const float* __restrict__ W2L,
                                            const float* __restrict__ b2L,
                                            const float* __restrict__ h_in,
                                            unsigned short* __restrict__ WbT0,
                                            unsigned short* __restrict__ WbTL,
                                            unsigned short* __restrict__ xb0) {
  const int y = blockIdx.y, t = threadIdx.x;
  if (y == 4) {
    for (int idx = blockIdx.x * 256 + t; idx < N_NODES * 32; idx += 65 * 256) {
      int n = idx >> 5, i = idx & 31;
      xb0[idx] = f2bf(i < IN_DIM ? h_in[n * IN_DIM + i] : 0.0f);
    }
    return;
  }
  __shared__ unsigned short tile[128 * 130];
  const int k = blockIdx.x;
  if (y == 0) {
    const float* src = (k < 64) ? (W2_0 + (size_t)k * IN_DIM * HID) : b2_0;
    for (int j = t; j < IN_DIM * HID; j += 256) {
      int i = j >> 7, o = j & 127;
      tile[i * 130 + o] = f2bf(src[j]);
    }
    __syncthreads();
    for (int j = t; j < HID * 32; j += 256) {
      int o = j >> 5, i = j & 31;
      WbT0[((size_t)k * HID + o) * 32 + i] =
          (i < IN_DIM) ? tile[i * 130 + o] : (unsigned short)0;
    }
  } else {
    const int l = y - 1;
    const float* src = (k < 64) ? (W2L + ((size_t)l * 64 + k) * (HID * HID))
                                : (b2L + (size_t)l * (HID * HID));
    unsigned short* dstp = WbTL + (size_t)l * ZCOLS * HID;
    for (int j = t; j < HID * HID; j += 256) {
      int i = j >> 7, o = j & 127;
      tile[i * 130 + o] = f2bf(src[j]);
    }
    __syncthreads();
    for (int j = t; j < HID * HID; j += 256) {
      int o = j >> 7, i = j & 127;
      dstp[((size_t)k * HID + o) * HID + i] = tile[i * 130 + o];
    }
  }
}

template <int KP, int SWZ>
__global__ __launch_bounds__(256) void gemm_z(const unsigned short* __restrict__ Xb,
                                              const unsigned short* __restrict__ WbT,
                                              unsigned short* __restrict__ Z) {
  extern __shared__ unsigned short lds[];
  unsigned short* Al = lds;
  unsigned short* Bl = lds + 128 * KP;
  const int nb = blockIdx.x;
  const int mb = blockIdx.y;
  const int t = threadIdx.x;
  const int ROWB = KP * 2;
  const int NCH = 128 * ROWB / 16;
  const unsigned short* Asrc = Xb + (size_t)mb * 128 * KP;
  const unsigned short* Bsrc = WbT + (size_t)nb * 128 * KP;
  for (int c = t; c < NCH; c += 256) {
    int off = c * 16;
    int row = off / ROWB;
    int kb = off % ROWB;
    int dsto = row * ROWB + (kb ^ ((row & SWZ) << 4));
    *(uint4*)((char*)Al + dsto) = *(const uint4*)((const char*)Asrc + off);
    *(uint4*)((char*)Bl + dsto) = *(const uint4*)((const char*)Bsrc + off);
  }
  __syncthreads();
  const int w = t >> 6, l = t & 63;
  const int wm = (w >> 1) * 64, wn = (w & 1) * 64;
  const int lr = l & 15, lh = l >> 4;
  f32x4 acc[4][4] = {};
#pragma unroll
  for (int kk = 0; kk < KP; kk += 32) {
    short8 a[4], b[4];
    const int kb = (kk + lh * 8) * 2;
#pragma unroll
    for (int mi = 0; mi < 4; ++mi) {
      int row = wm + mi * 16 + lr;
      int addr = row * ROWB + (kb ^ ((row & SWZ) << 4));
      a[mi] = *(const short8*)((const char*)Al + addr);
    }
#pragma unroll
    for (int ni = 0; ni < 4; ++ni) {
      int col = wn + ni * 16 + lr;
      int addr = col * ROWB + (kb ^ ((col & SWZ) << 4));
      b[ni] = *(const short8*)((const char*)Bl + addr);
    }
#pragma unroll
    for (int mi = 0; mi < 4; ++mi)
#pragma unroll
      for (int ni = 0; ni < 4; ++ni)
        acc[mi][ni] = __builtin_amdgcn_mfma_f32_16x16x32_bf16(b[ni], a[mi], acc[mi][ni], 0, 0, 0);
  }
#pragma unroll
  for (int mi = 0; mi < 4; ++mi) {
    const int node = mb * 128 + wm + mi * 16 + lr;
    unsigned short* zp = Z + (size_t)node * ZCOLS + nb * 128 + wn + lh * 4;
#pragma unroll
    for (int ni = 0; ni < 4; ++ni) {
      ushort4 pk;
      pk.x = f2bf(acc[mi][ni][0]);
      pk.y = f2bf(acc[mi][ni][1]);
      pk.z = f2bf(acc[mi][ni][2]);
      pk.w = f2bf(acc[mi][ni][3]);
      *(ushort4*)(zp + ni * 16) = pk;
    }
  }
}

template <int LAST>
__global__ __launch_bounds__(128) void node_gather(
    const float* __restrict__ efeat, const float* __restrict__ W1,
    const float* __restrict__ b1, const unsigned short* __restrict__ Z,
    const int* __restrict__ elist, const int* __restrict__ roff,
    const int* __restrict__ src,
    const float* __restrict__ bias, const float* __restrict__ gamma,
    const float* __restrict__ beta, const float* __restrict__ mean,
    const float* __restrict__ var,
    unsigned short* __restrict__ xbout,
    const int* __restrict__ ng, float* __restrict__ gsum,
    unsigned int* __restrict__ gmax, float* __restrict__ gcnt) {
  const int n = blockIdx.x, t = threadIdx.x;
  const int cg2 = t & 15, kg = t >> 4;
  const int start = roff[n], end = roff[n + 1];
  __shared__ float hs[EDGE_H];
  __shared__ float red[128][9];
  float acc8[8] = {};
  for (int idx = start; idx < end; ++idx) {
    const int e = elist[idx];
    __syncthreads();
    if (t < EDGE_H) {
      float a = b1[t];
#pragma unroll
      for (int j = 0; j < E_DIMF; ++j) a += efeat[e * E_DIMF + j] * W1[j * EDGE_H + t];
      hs[t] = fmaxf(a, 0.f);
    }
    __syncthreads();
    const unsigned short* zr = Z + (size_t)src[e] * ZCOLS + cg2 * 8;
#pragma unroll
    for (int kk = 0; kk < 8; ++kk) {
      const int k = kg * 8 + kk;
      short8 v = *(const short8*)(zr + k * HID);
      const float hk = hs[k];
#pragma unroll
      for (int j = 0; j < 8; ++j) acc8[j] += hk * bf2f((unsigned short)v[j]);
    }
    if (kg == 0) {
      short8 v = *(const short8*)(zr + 64 * HID);
#pragma unroll
      for (int j = 0; j < 8; ++j) acc8[j] += bf2f((unsigned short)v[j]);
    }
  }
#pragma unroll
  for (int j = 0; j < 8; ++j) red[t][j] = acc8[j];
  __syncthreads();
  const int o = t;
  float s = 0.f;
#pragma unroll
  for (int k2 = 0; k2 < 8; ++k2) s += red[k2 * 16 + (o >> 3)][o & 7];
  const int dg = end - start;
  float v = s / (float)(dg > 0 ? dg : 1) + bias[o];
  v = fmaxf(v, 0.f);
  v = (v - mean[o]) * rsqrtf(var[o] + BN_EPS) * gamma[o] + beta[o];
  if (!LAST) {
    xbout[n * HID + o] = f2bf(v);
  } else {
    const int g = ng[n];
    atomicAdd(&gsum[g * HID + o], v);
    unsigned int u = __float_as_uint(v);
    unsigned int key = (u & 0x80000000u) ? ~u : (u | 0x80000000u);
    atomicMax(&gmax[g * HID + o], key);
    if (o == 0) atomicAdd(&gcnt[g], 1.f);
  }
}

__global__ void out_final(const float* __restrict__ gsum, const unsigned int* __restrict__ gmax,
                          const float* __restrict__ gcnt,
                          const float* __restrict__ g_out, const float* __restrict__ b_out,
                          const float* __restrict__ m_out, const float* __restrict__ v_out,
                          float* __restrict__ out) {
  int g = blockIdx.x, t = threadIdx.x;
  float hn = gsum[g * HID + t] / fmaxf(gcnt[g], 1.0f);
  hn = (hn - m_out[t]) * rsqrtf(v_out[t] + BN_EPS) * g_out[t] + b_out[t];
  unsigned int key = gmax[g * HID + t];
  unsigned int u = (key & 0x80000000u) ? (key ^ 0x80000000u) : ~key;
  out[g * 2 * HID + t] = hn;
  out[g * 2 * HID + HID + t] = __uint_as_float(u);
}

// ================================ host ========================================

extern "C" void kernel_launch(void* const* d_in, const int* in_sizes, int n_in,
                              void* d_out, int out_size, void* d_ws, size_t ws_size,
                              hipStream_t stream) {
  char* ws = (char*)d_ws;
  size_t off = 0;
  auto alloc = [&](size_t bytes) {
    void* pp = ws + off;
    off = (off + bytes + 255) & ~(size_t)255;
    return pp;
  };

  MegaP P;
  P.h_in    = (const float*)d_in[0];
  P.e_in    = (const float*)d_in[1];
  P.src     = (const int*)d_in[2];
  P.dst     = (const int*)d_in[3];
  P.ng      = (const int*)d_in[4];
  P.eW1_0   = (const float*)d_in[5];
  P.eb1_0   = (const float*)d_in[6];
  P.eW2_0   = (const float*)d_in[7];
  P.eb2_0   = (const float*)d_in[8];
  P.bias_0  = (const float*)d_in[9];
  P.gamma_0 = (const float*)d_in[10];
  P.beta_0  = (const float*)d_in[11];
  P.mean_0  = (const float*)d_in[12];
  P.var_0   = (const float*)d_in[13];
  P.eW1     = (const float*)d_in[14];
  P.eb1     = (const float*)d_in[15];
  P.eW2     = (const float*)d_in[16];
  P.eb2     = (const float*)d_in[17];
  P.biasL   = (const float*)d_in[18];
  P.gammaL  = (const float*)d_in[19];
  P.betaL   = (const float*)d_in[20];
  P.meanL   = (const float*)d_in[21];
  P.varL    = (const float*)d_in[22];
  P.g_out   = (const float*)d_in[23];
  P.b_out   = (const float*)d_in[24];
  P.m_out   = (const float*)d_in[25];
  P.v_out   = (const float*)d_in[26];
  P.out     = (float*)d_out;

  P.Z     = (unsigned short*)alloc((size_t)N_NODES * ZCOLS * 2);
  P.WbT0  = (unsigned short*)alloc((size_t)ZCOLS * 32 * 2);
  P.WbTL  = (unsigned short*)alloc((size_t)3 * ZCOLS * HID * 2);
  P.xb0   = (unsigned short*)alloc((size_t)N_NODES * 32 * 2);
  P.xb    = (unsigned short*)alloc((size_t)N_NODES * HID * 2);
  P.gsum  = (float*)alloc((size_t)N_GRAPH * HID * 4);
  P.gmax  = (unsigned int*)alloc((size_t)N_GRAPH * HID * 4);
  P.gcnt  = (float*)alloc((size_t)N_GRAPH * 4);
  int* degi = (int*)alloc((size_t)N_NODES * 4);
  P.roff  = (int*)alloc((size_t)(N_NODES + 1) * 4);
  P.cursor= (int*)alloc((size_t)N_NODES * 4);
  P.elist = (int*)alloc((size_t)N_EDGES * 4);

  // ---- decide path: cooperative mega vs multi-kernel fallback ----
  int dev = 0;
  hipGetDevice(&dev);
  int coopAttr = 0;
  hipDeviceGetAttribute(&coopAttr, hipDeviceAttributeCooperativeLaunch, dev);
  int maxBlk = 0;
  hipError_t occErr = hipOccupancyMaxActiveBlocksPerMultiprocessor(
      &maxBlk, (const void*)mega, MEGA_THREADS, 65536);
  bool useCoop = (coopAttr != 0) && (occErr == hipSuccess) && (maxBlk >= 1);

  if (useCoop) {
    void* args[] = {(void*)&P};
    hipError_t lerr = hipLaunchCooperativeKernel((const void*)mega, dim3(MEGA_BLOCKS),
                                                 dim3(MEGA_THREADS), args, 65536, stream);
    if (lerr == hipSuccess) return;
    // fall through to fallback on synchronous launch failure
  }

  // ---- fallback: verified R3 multi-kernel path ----
  hipMemsetAsync(P.gsum, 0,
                 (size_t)((char*)(degi + N_NODES) - (char*)P.gsum), stream);
  calc_deg_i<<<N_EDGES / 256, 256, 0, stream>>>(P.dst, degi);
  build_offsets<<<1, 256, 0, stream>>>(degi, P.roff, P.cursor);
  scatter_edges<<<N_EDGES / 256, 256, 0, stream>>>(P.dst, P.cursor, P.elist);
  prep<<<dim3(65, 5), 256, 0, stream>>>(P.eW2_0, P.eb2_0, P.eW2, P.eb2, P.h_in,
                                        P.WbT0, P.WbTL, P.xb0);

  gemm_z<32, 3><<<dim3(65, 16), 256, 2 * 128 * 32 * 2, stream>>>(P.xb0, P.WbT0, P.Z);
  node_gather<0><<<N_NODES, 128, 0, stream>>>(P.e_in, P.eW1_0, P.eb1_0, P.Z, P.elist,
                                              P.roff, P.src, P.bias_0, P.gamma_0,
                                              P.beta_0, P.mean_0, P.var_0, P.xb,
                                              P.ng, P.gsum, P.gmax, P.gcnt);
  for (int l = 0; l < 3; ++l) {
    gemm_z<128, 7><<<dim3(65, 16), 256, 2 * 128 * 128 * 2, stream>>>(
        P.xb, P.WbTL + (size_t)l * ZCOLS * HID, P.Z);
    if (l < 2)
      node_gather<0><<<N_NODES, 128, 0, stream>>>(
          P.e_in, P.eW1 + l * E_DIMF * EDGE_H, P.eb1 + l * EDGE_H, P.Z, P.elist,
          P.roff, P.src, P.biasL + l * HID, P.gammaL + l * HID, P.betaL + l * HID,
          P.meanL + l * HID, P.varL + l * HID, P.xb, P.ng, P.gsum, P.gmax, P.gcnt);
    else
      node_gather<1><<<N_NODES, 128, 0, stream>>>(
          P.e_in, P.eW1 + l * E_DIMF * EDGE_H, P.eb1 + l * EDGE_H, P.Z, P.elist,
          P.roff, P.src, P.biasL + l * HID, P.gammaL + l * HID, P.betaL + l * HID,
          P.meanL + l * HID, P.varL + l * HID, P.xb, P.ng, P.gsum, P.gmax, P.gcnt);
  }
  out_final<<<N_GRAPH, HID, 0, stream>>>(P.gsum, P.gmax, P.gcnt, P.g_out, P.b_out,
                                         P.m_out, P.v_out, P.out);
}